// Round 10
// baseline (527.694 us; speedup 1.0000x reference)
//
#include <hip/hip_runtime.h>
#include <hip/hip_bf16.h>

#define NBMAX 128   // max dst-buckets (N/1024); N=100K -> 98

typedef __attribute__((ext_vector_type(8))) short short8;   // 8 bf16 (4 VGPR) MFMA operand
typedef __attribute__((ext_vector_type(4))) float f32x4;    // MFMA accumulator

// ---- bf16 helpers (RNE) ----
__device__ inline unsigned short bf16_rne(float x) {
    unsigned u = __float_as_uint(x);
    u = (u + 0x7FFFu + ((u >> 16) & 1u)) >> 16;
    return (unsigned short)u;
}
__device__ inline float bf16_to_f(unsigned short h) {
    return __uint_as_float(((unsigned)h) << 16);
}
__device__ inline void split2(float v, short& h, short& lo) {
    unsigned short hb = bf16_rne(v);
    h = (short)hb;
    lo = (short)bf16_rne(v - bf16_to_f(hb));
}

// ---------------- preprocessing (bucket pipeline, no per-node device atomics) ----
// pairs are packed: bits 0..16 = src (N < 2^17), bits 17..26 = dst low-10 bits.

__global__ __launch_bounds__(256) void k_bcnt(const int* __restrict__ dst, int E, int NB,
                                              int* __restrict__ bucket_cnt) {
    __shared__ int lcnt[NBMAX];
    int t = threadIdx.x;
    int base = blockIdx.x * 4096;
    for (int i = t; i < NB; i += 256) lcnt[i] = 0;
    __syncthreads();
#pragma unroll
    for (int i = 0; i < 16; i++) {
        int e = base + i * 256 + t;
        if (e < E) atomicAdd(&lcnt[dst[e] >> 10], 1);
    }
    __syncthreads();
    for (int i = t; i < NB; i += 256) {
        int c = lcnt[i];
        if (c) atomicAdd(&bucket_cnt[i], c);
    }
}

__global__ __launch_bounds__(128) void k_bscan(const int* __restrict__ bucket_cnt,
                                               int NB, int E, int N,
                                               int* __restrict__ bucket_off,
                                               int* __restrict__ bcur,
                                               int* __restrict__ rowstart) {
    __shared__ int sh[128];
    int t = threadIdx.x;
    int v = (t < NB) ? bucket_cnt[t] : 0;
    sh[t] = v;
    __syncthreads();
    for (int off = 1; off < 128; off <<= 1) {
        int x = (t >= off) ? sh[t - off] : 0;
        __syncthreads();
        sh[t] += x;
        __syncthreads();
    }
    if (t < NB) {
        int excl = sh[t] - v;
        bucket_off[t] = excl;
        bcur[t] = excl;
    }
    if (t == 0) {
        bucket_off[NB] = E;
        rowstart[N] = E;
    }
}

__global__ __launch_bounds__(256) void k_bucket(const int* __restrict__ src,
                                                const int* __restrict__ dst, int E, int NB,
                                                int* __restrict__ bcur,
                                                unsigned* __restrict__ pairs) {
    __shared__ int lcnt[NBMAX];
    __shared__ int gbase[NBMAX];
    int t = threadIdx.x;
    int base = blockIdx.x * 4096;
    for (int i = t; i < NB; i += 256) lcnt[i] = 0;
    __syncthreads();
    int rank[16];
#pragma unroll
    for (int i = 0; i < 16; i++) {
        int e = base + i * 256 + t;
        rank[i] = (e < E) ? atomicAdd(&lcnt[dst[e] >> 10], 1) : -1;
    }
    __syncthreads();
    for (int i = t; i < NB; i += 256) {
        int c = lcnt[i];
        gbase[i] = c ? atomicAdd(&bcur[i], c) : 0;
    }
    __syncthreads();
#pragma unroll
    for (int i = 0; i < 16; i++) {
        int e = base + i * 256 + t;
        if (e < E) {
            int d = dst[e];
            pairs[gbase[d >> 10] + rank[i]] =
                ((unsigned)(d & 1023) << 17) | (unsigned)src[e];
        }
    }
}

__global__ __launch_bounds__(1024) void k_node(const unsigned* __restrict__ pairs,
                                               const int* __restrict__ bucket_off, int N,
                                               int* __restrict__ rowstart,
                                               float* __restrict__ dinv,
                                               int* __restrict__ csr_src) {
    __shared__ int cnt_l[1024];
    __shared__ int cur_l[1024];
    __shared__ int wsum[16];
    int t = threadIdx.x;
    int lane = t & 63, wv = t >> 6;
    int b = blockIdx.x;
    int n0 = b << 10;
    int nn = min(1024, N - n0);
    cnt_l[t] = 0;
    __syncthreads();
    int e0 = bucket_off[b], e1 = bucket_off[b + 1];
    for (int e = e0 + t; e < e1; e += 1024) {
        atomicAdd(&cnt_l[pairs[e] >> 17], 1);
    }
    __syncthreads();
    int c = cnt_l[t];
    int v = c;
#pragma unroll
    for (int off = 1; off < 64; off <<= 1) {
        int x = __shfl_up(v, off);
        if (lane >= off) v += x;
    }
    if (lane == 63) wsum[wv] = v;
    __syncthreads();
    if (wv == 0 && lane < 16) {
        int wval = wsum[lane];
#pragma unroll
        for (int off = 1; off < 16; off <<= 1) {
            int x = __shfl_up(wval, off);
            if (lane >= off) wval += x;
        }
        wsum[lane] = wval;
    }
    __syncthreads();
    int prefix = (wv > 0) ? wsum[wv - 1] : 0;
    int start = e0 + prefix + v - c;
    cur_l[t] = start;
    if (t < nn) {
        rowstart[n0 + t] = start;
        dinv[n0 + t] = rsqrtf((float)c + 1.0f);
    }
    __syncthreads();
    for (int e = e0 + t; e < e1; e += 1024) {
        unsigned p = pairs[e];
        int r = atomicAdd(&cur_l[p >> 17], 1);
        csr_src[r] = (int)(p & 0x1FFFFu);
    }
}

// ---------------- W prep (all 3 weights) + bucket_cnt zeroing ----------------
__global__ __launch_bounds__(256) void k_wprep3(const float* __restrict__ W1,
                                                const float* __restrict__ W2,
                                                const float* __restrict__ W3,
                                                unsigned short* __restrict__ WH,
                                                unsigned short* __restrict__ WL,
                                                int* __restrict__ bucket_cnt) {
    if (blockIdx.x == 0 && threadIdx.x < NBMAX) bucket_cnt[threadIdx.x] = 0;
    int wi = blockIdx.x >> 6;
    int idx = (blockIdx.x & 63) * 256 + threadIdx.x;
    const float* W = (wi == 0) ? W1 : (wi == 1) ? W2 : W3;
    int j = idx & 7;
    int lane = (idx >> 3) & 63;
    int ct = (idx >> 9) & 7;
    int kc = idx >> 12;
    int k = kc * 32 + (lane >> 4) * 8 + j;
    int col = ct * 16 + (lane & 15);
    float v = W[k * 128 + col];
    unsigned short hb = bf16_rne(v);
    WH[wi * 16384 + idx] = hb;
    WL[wi * 16384 + idx] = bf16_rne(v - bf16_to_f(hb));
}

// ---------------- GEMM: U = bf16(dinv .* (A @ W)) via 3-term bf16 MFMA ----------
// A*W ~= Ah*Wh + Ah*Wl + Al*Wh. R9's divergent per-lane A gathers (16-row visits
// per VMEM instr) replaced by LDS staging: block-coalesced float4 loads, frag
// reads from LDS (pad 34 -> 2-way bank alias only, free). Epilogue stages bf16
// output in LDS (pad 132) then stores coalesced uint2 rows. A-stage and U-stage
// share one 34KB union.

__global__ __launch_bounds__(256) void k_gemm3(const float* __restrict__ A,
                                               const unsigned short* __restrict__ WH,
                                               const unsigned short* __restrict__ WL,
                                               const float* __restrict__ dinv,
                                               unsigned short* __restrict__ U, int N) {
    __shared__ __align__(16) char smem[128 * 132 * 2];   // 33.8KB union
    float (*Ash)[34] = (float(*)[34])smem;               // 128 x 34 f32 (17.4KB)
    unsigned short (*Ust)[132] = (unsigned short(*)[132])smem;  // 128 x 132 bf16

    int t = threadIdx.x;
    int wv = t >> 6;
    int l = t & 63;
    int quad = l >> 4;
    int lm = l & 15;
    int rowBase = blockIdx.x * 128;

    f32x4 acc[2][8] = {};

    for (int kc = 0; kc < 4; kc++) {
        // global loads first (latency overlap), then publish to LDS
        float4 v[4];
#pragma unroll
        for (int i = 0; i < 4; i++) {
            int idx = t + i * 256;          // 0..1023 float4 slots
            int row = idx >> 3;             // 8 float4 per row
            int c4 = idx & 7;
            int gr = rowBase + row;
            v[i] = make_float4(0.f, 0.f, 0.f, 0.f);
            if (gr < N) v[i] = *(const float4*)&A[(size_t)gr * 128 + kc * 32 + c4 * 4];
        }
        __syncthreads();   // previous chunk's frag reads complete
#pragma unroll
        for (int i = 0; i < 4; i++) {
            int idx = t + i * 256;
            int row = idx >> 3;
            int c4 = idx & 7;
            *(float2*)&Ash[row][c4 * 4] = make_float2(v[i].x, v[i].y);
            *(float2*)&Ash[row][c4 * 4 + 2] = make_float2(v[i].z, v[i].w);
        }
        __syncthreads();   // staging complete

        // fragment reads from LDS: wave wv covers local rows wv*32 .. +31
        int lr0 = wv * 32 + lm;
        int lr1 = wv * 32 + 16 + lm;
        float av0[8], av1[8];
#pragma unroll
        for (int jj = 0; jj < 4; jj++) {
            float2 p0 = *(const float2*)&Ash[lr0][quad * 8 + jj * 2];
            float2 p1 = *(const float2*)&Ash[lr1][quad * 8 + jj * 2];
            av0[jj * 2] = p0.x; av0[jj * 2 + 1] = p0.y;
            av1[jj * 2] = p1.x; av1[jj * 2 + 1] = p1.y;
        }
        short8 ah0, al0, ah1, al1;
#pragma unroll
        for (int j = 0; j < 8; j++) {
            short h, lo;
            split2(av0[j], h, lo); ah0[j] = h; al0[j] = lo;
            split2(av1[j], h, lo); ah1[j] = h; al1[j] = lo;
        }
#pragma unroll
        for (int ct = 0; ct < 8; ct++) {
            size_t fo = ((size_t)(kc * 8 + ct) * 64 + l) * 8;
            short8 wh = *(const short8*)&WH[fo];
            short8 wl = *(const short8*)&WL[fo];
            acc[0][ct] = __builtin_amdgcn_mfma_f32_16x16x32_bf16(ah0, wh, acc[0][ct], 0, 0, 0);
            acc[0][ct] = __builtin_amdgcn_mfma_f32_16x16x32_bf16(ah0, wl, acc[0][ct], 0, 0, 0);
            acc[0][ct] = __builtin_amdgcn_mfma_f32_16x16x32_bf16(al0, wh, acc[0][ct], 0, 0, 0);
            acc[1][ct] = __builtin_amdgcn_mfma_f32_16x16x32_bf16(ah1, wh, acc[1][ct], 0, 0, 0);
            acc[1][ct] = __builtin_amdgcn_mfma_f32_16x16x32_bf16(ah1, wl, acc[1][ct], 0, 0, 0);
            acc[1][ct] = __builtin_amdgcn_mfma_f32_16x16x32_bf16(al1, wh, acc[1][ct], 0, 0, 0);
        }
    }

    // epilogue: C/D map col=lane&15, row=quad*4+reg (m89-verified).
    __syncthreads();   // all frag reads done; smem now re-used as Ust
#pragma unroll
    for (int rt = 0; rt < 2; rt++) {
#pragma unroll
        for (int reg = 0; reg < 4; reg++) {
            int lrow = wv * 32 + rt * 16 + quad * 4 + reg;
            int grow_ = rowBase + lrow;
            float dv = (grow_ < N) ? dinv[grow_] : 0.f;
#pragma unroll
            for (int ct = 0; ct < 8; ct++) {
                Ust[lrow][ct * 16 + lm] = bf16_rne(dv * acc[rt][ct][reg]);
            }
        }
    }
    __syncthreads();
    // coalesced store: 128 rows x 256B
#pragma unroll
    for (int i = 0; i < 16; i++) {
        int idx = t + i * 256;      // 0..4095 uint2 slots
        int row = idx >> 5;         // 32 uint2 per row
        int c = idx & 31;
        int gr = rowBase + row;
        if (gr < N) {
            uint2 vv = *(const uint2*)&Ust[row][c * 4];
            *(uint2*)&U[(size_t)gr * 128 + c * 4] = vv;
        }
    }
}

// ---------------- aggregation ----------------
// H[n] = relu(dinv[n]*(U[n] + sum_e U[src_e]) + b) (+H if RES).
// Pinned at ~73us/layer by distinct-row-visit throughput (R7/R8/R9 A/B):
// 1.7M visits/layer @ ~26 CU-cycles each. Structure kept from R9.

template <int RES>
__global__ __launch_bounds__(256) void k_agg(const unsigned short* __restrict__ U,
                                             const int* __restrict__ rowstart,
                                             const int* __restrict__ csr_src,
                                             const float* __restrict__ dinv,
                                             const float* __restrict__ bias,
                                             float* __restrict__ H, int N) {
    int wave = threadIdx.x >> 6;  // 0..3
    int lane = threadIdx.x & 63;
    int n = blockIdx.x * 4 + wave;
    if (n >= N) return;
    int grp = lane >> 4;   // edge group 0..3
    int li = lane & 15;    // channel octet: li*8 .. li*8+7
    int e0 = rowstart[n], e1 = rowstart[n + 1];
    int len = e1 - e0;
    int q0 = e0 + ((len * grp) >> 2);
    int q1 = e0 + ((len * (grp + 1)) >> 2);

    float a0 = 0.f, a1 = 0.f, a2 = 0.f, a3 = 0.f;
    float a4 = 0.f, a5 = 0.f, a6 = 0.f, a7 = 0.f;
    float b0 = 0.f, b1 = 0.f, b2 = 0.f, b3 = 0.f;
    float b4 = 0.f, b5 = 0.f, b6 = 0.f, b7 = 0.f;

    int e = q0;
    for (; e + 2 <= q1; e += 2) {
        int s0 = csr_src[e];
        int s1 = csr_src[e + 1];
        uint4 r0 = *(const uint4*)&U[(size_t)s0 * 128 + li * 8];
        uint4 r1 = *(const uint4*)&U[(size_t)s1 * 128 + li * 8];
        a0 += __uint_as_float(r0.x << 16);        a1 += __uint_as_float(r0.x & 0xFFFF0000u);
        a2 += __uint_as_float(r0.y << 16);        a3 += __uint_as_float(r0.y & 0xFFFF0000u);
        a4 += __uint_as_float(r0.z << 16);        a5 += __uint_as_float(r0.z & 0xFFFF0000u);
        a6 += __uint_as_float(r0.w << 16);        a7 += __uint_as_float(r0.w & 0xFFFF0000u);
        b0 += __uint_as_float(r1.x << 16);        b1 += __uint_as_float(r1.x & 0xFFFF0000u);
        b2 += __uint_as_float(r1.y << 16);        b3 += __uint_as_float(r1.y & 0xFFFF0000u);
        b4 += __uint_as_float(r1.z << 16);        b5 += __uint_as_float(r1.z & 0xFFFF0000u);
        b6 += __uint_as_float(r1.w << 16);        b7 += __uint_as_float(r1.w & 0xFFFF0000u);
    }
    if (e < q1) {
        int s0 = csr_src[e];
        uint4 r0 = *(const uint4*)&U[(size_t)s0 * 128 + li * 8];
        a0 += __uint_as_float(r0.x << 16);        a1 += __uint_as_float(r0.x & 0xFFFF0000u);
        a2 += __uint_as_float(r0.y << 16);        a3 += __uint_as_float(r0.y & 0xFFFF0000u);
        a4 += __uint_as_float(r0.z << 16);        a5 += __uint_as_float(r0.z & 0xFFFF0000u);
        a6 += __uint_as_float(r0.w << 16);        a7 += __uint_as_float(r0.w & 0xFFFF0000u);
    }
    a0 += b0; a1 += b1; a2 += b2; a3 += b3;
    a4 += b4; a5 += b5; a6 += b6; a7 += b7;

    a0 += __shfl_xor(a0, 16); a1 += __shfl_xor(a1, 16);
    a2 += __shfl_xor(a2, 16); a3 += __shfl_xor(a3, 16);
    a4 += __shfl_xor(a4, 16); a5 += __shfl_xor(a5, 16);
    a6 += __shfl_xor(a6, 16); a7 += __shfl_xor(a7, 16);
    a0 += __shfl_xor(a0, 32); a1 += __shfl_xor(a1, 32);
    a2 += __shfl_xor(a2, 32); a3 += __shfl_xor(a3, 32);
    a4 += __shfl_xor(a4, 32); a5 += __shfl_xor(a5, 32);
    a6 += __shfl_xor(a6, 32); a7 += __shfl_xor(a7, 32);

    if (grp == 0) {
        uint4 qs = *(const uint4*)&U[(size_t)n * 128 + li * 8];
        float4 bi0 = *(const float4*)&bias[li * 8];
        float4 bi1 = *(const float4*)&bias[li * 8 + 4];
        float dn = dinv[n];
        float4 o0, o1v;
        o0.x = fmaxf(dn * (a0 + __uint_as_float(qs.x << 16)) + bi0.x, 0.f);
        o0.y = fmaxf(dn * (a1 + __uint_as_float(qs.x & 0xFFFF0000u)) + bi0.y, 0.f);
        o0.z = fmaxf(dn * (a2 + __uint_as_float(qs.y << 16)) + bi0.z, 0.f);
        o0.w = fmaxf(dn * (a3 + __uint_as_float(qs.y & 0xFFFF0000u)) + bi0.w, 0.f);
        o1v.x = fmaxf(dn * (a4 + __uint_as_float(qs.z << 16)) + bi1.x, 0.f);
        o1v.y = fmaxf(dn * (a5 + __uint_as_float(qs.z & 0xFFFF0000u)) + bi1.y, 0.f);
        o1v.z = fmaxf(dn * (a6 + __uint_as_float(qs.w << 16)) + bi1.z, 0.f);
        o1v.w = fmaxf(dn * (a7 + __uint_as_float(qs.w & 0xFFFF0000u)) + bi1.w, 0.f);
        size_t hi = (size_t)n * 128 + li * 8;
        if (RES) {
            float4 h0 = *(const float4*)&H[hi];
            float4 h1 = *(const float4*)&H[hi + 4];
            o0.x += h0.x; o0.y += h0.y; o0.z += h0.z; o0.w += h0.w;
            o1v.x += h1.x; o1v.y += h1.y; o1v.z += h1.z; o1v.w += h1.w;
        }
        *(float4*)&H[hi] = o0;
        *(float4*)&H[hi + 4] = o1v;
    }
}

// ---------------- fused pooling + MLP head ----------------

__global__ __launch_bounds__(256) void k_head(const float* __restrict__ H,
                                              const int* __restrict__ batch, int N, int G,
                                              const float* __restrict__ Wf1,
                                              const float* __restrict__ bf1,
                                              const float* __restrict__ Wf2,
                                              const float* __restrict__ bf2,
                                              const float* __restrict__ Wf3,
                                              const float* __restrict__ bf3,
                                              float* __restrict__ out) {
    __shared__ float ssum[256];
    __shared__ float smax[256];
    __shared__ float grow[256];
    __shared__ float o1[128];
    __shared__ float o2[64];
    int g = blockIdx.x;
    int t = threadIdx.x;
    int i0, i1;
    {
        int lo = 0, hi = N;
        while (lo < hi) { int m = (lo + hi) >> 1; if (batch[m] < g) lo = m + 1; else hi = m; }
        i0 = lo;
        lo = i0; hi = N;
        while (lo < hi) { int m = (lo + hi) >> 1; if (batch[m] < g + 1) lo = m + 1; else hi = m; }
        i1 = lo;
    }
    int c = t & 127;
    int half = t >> 7;
    int cn = i1 - i0;
    int mid = i0 + (cn >> 1);
    int a0 = half ? mid : i0;
    int a1 = half ? i1 : mid;
    float s = 0.f, m = -3.4e38f;
    for (int i = a0; i < a1; i++) {
        float v = H[(size_t)i * 128 + c];
        s += v;
        m = fmaxf(m, v);
    }
    ssum[t] = s;
    smax[t] = m;
    __syncthreads();
    if (half == 0) {
        float st = ssum[c] + ssum[c + 128];
        float mt = fmaxf(smax[c], smax[c + 128]);
        grow[c] = (cn > 0) ? st / (float)cn : 0.f;
        grow[128 + c] = (cn > 0) ? mt : 0.f;
    }
    __syncthreads();
    if (t < 128) {
        float acc = bf1[t];
#pragma unroll 8
        for (int k = 0; k < 256; k++) acc = fmaf(grow[k], Wf1[k * 128 + t], acc);
        o1[t] = fmaxf(acc, 0.f);
    }
    __syncthreads();
    if (t < 64) {
        float a2 = bf2[t];
#pragma unroll 8
        for (int k = 0; k < 128; k++) a2 = fmaf(o1[k], Wf2[k * 64 + t], a2);
        o2[t] = fmaxf(a2, 0.f);
    }
    __syncthreads();
    if (t < 64) {
        float p = o2[t] * Wf3[t];
        for (int off = 32; off > 0; off >>= 1) p += __shfl_down(p, off);
        if (t == 0) out[g] = p + bf3[0];
    }
}

// ---------------- launch ----------------

extern "C" void kernel_launch(void* const* d_in, const int* in_sizes, int n_in,
                              void* d_out, int out_size, void* d_ws, size_t ws_size,
                              hipStream_t stream) {
    const float* x = (const float*)d_in[0];
    const int* ei = (const int*)d_in[1];
    const int* batch = (const int*)d_in[2];
    const float* W1 = (const float*)d_in[4];
    const float* b1 = (const float*)d_in[5];
    const float* W2 = (const float*)d_in[6];
    const float* b2 = (const float*)d_in[7];
    const float* W3 = (const float*)d_in[8];
    const float* b3 = (const float*)d_in[9];
    const float* Wf1 = (const float*)d_in[10];
    const float* bf1 = (const float*)d_in[11];
    const float* Wf2 = (const float*)d_in[12];
    const float* bf2 = (const float*)d_in[13];
    const float* Wf3 = (const float*)d_in[14];
    const float* bf3 = (const float*)d_in[15];

    const int N = in_sizes[0] / 128;
    const int E = in_sizes[1] / 2;
    const int G = out_size;

    const int* src = ei;
    const int* dst = ei + E;

    char* w = (char*)d_ws;
    size_t off = 0;
    auto alloc = [&](size_t bytes) -> void* {
        void* p = w + off;
        off += (bytes + 255) / 256 * 256;
        return p;
    };
    unsigned short* U = (unsigned short*)alloc((size_t)N * 128 * 2);
    float* H = (float*)alloc((size_t)N * 128 * 4);
    unsigned* pairs = (unsigned*)alloc((size_t)E * 4);   // packed (dlow<<17)|src
    int* csr_src = (int*)alloc((size_t)E * 4);
    int* rowstart = (int*)alloc((size_t)(N + 1) * 4);
    float* dinv = (float*)alloc((size_t)N * 4);
    int* bucket_cnt = (int*)alloc(NBMAX * 4);
    int* bucket_off = (int*)alloc((NBMAX + 1) * 4);
    int* bcur = (int*)alloc(NBMAX * 4);
    unsigned short* WH = (unsigned short*)alloc(3 * 16384 * 2);
    unsigned short* WL = (unsigned short*)alloc(3 * 16384 * 2);
    float* out = (float*)d_out;

    const int NB = (N + 1023) >> 10;
    const int ebk = (E + 4095) / 4096;

    k_wprep3<<<dim3(192), dim3(256), 0, stream>>>(W1, W2, W3, WH, WL, bucket_cnt);

    k_bcnt<<<dim3(ebk), dim3(256), 0, stream>>>(dst, E, NB, bucket_cnt);
    k_bscan<<<dim3(1), dim3(128), 0, stream>>>(bucket_cnt, NB, E, N, bucket_off, bcur, rowstart);
    k_bucket<<<dim3(ebk), dim3(256), 0, stream>>>(src, dst, E, NB, bcur, pairs);
    k_node<<<dim3(NB), dim3(1024), 0, stream>>>(pairs, bucket_off, N, rowstart, dinv, csr_src);

    const int gemmGrid = (N + 127) / 128;
    const int aggGrid = (N + 3) / 4;

    // conv1
    k_gemm3<<<dim3(gemmGrid), dim3(256), 0, stream>>>(x, WH, WL, dinv, U, N);
    k_agg<0><<<dim3(aggGrid), dim3(256), 0, stream>>>(U, rowstart, csr_src, dinv, b1, H, N);
    // conv2
    k_gemm3<<<dim3(gemmGrid), dim3(256), 0, stream>>>(H, WH + 16384, WL + 16384, dinv, U, N);
    k_agg<1><<<dim3(aggGrid), dim3(256), 0, stream>>>(U, rowstart, csr_src, dinv, b2, H, N);
    // conv3
    k_gemm3<<<dim3(gemmGrid), dim3(256), 0, stream>>>(H, WH + 32768, WL + 32768, dinv, U, N);
    k_agg<1><<<dim3(aggGrid), dim3(256), 0, stream>>>(U, rowstart, csr_src, dinv, b3, H, N);

    // fused pooling + MLP head
    k_head<<<dim3(G), dim3(256), 0, stream>>>(H, batch, N, G, Wf1, bf1, Wf2, bf2, Wf3, bf3, out);
}

// Round 11
// 496.449 us; speedup vs baseline: 1.0629x; 1.0629x over previous
//
#include <hip/hip_runtime.h>
#include <hip/hip_bf16.h>

#define NBMAX 256   // max dst-buckets (N/512); N=100K -> 196
#define BSH 9       // bucket shift: 512 nodes per bucket
#define BMSK 511
#define CHUNK 4096  // edges per k_bucket block
#define NCAP 10240  // k_node LDS staging capacity (edges); mean/bucket=8192, sd~90

typedef __attribute__((ext_vector_type(8))) short short8;   // 8 bf16 (4 VGPR) MFMA operand
typedef __attribute__((ext_vector_type(4))) float f32x4;    // MFMA accumulator

// ---- bf16 helpers (RNE) ----
__device__ inline unsigned short bf16_rne(float x) {
    unsigned u = __float_as_uint(x);
    u = (u + 0x7FFFu + ((u >> 16) & 1u)) >> 16;
    return (unsigned short)u;
}
__device__ inline float bf16_to_f(unsigned short h) {
    return __uint_as_float(((unsigned)h) << 16);
}
__device__ inline void split2(float v, short& h, short& lo) {
    unsigned short hb = bf16_rne(v);
    h = (short)hb;
    lo = (short)bf16_rne(v - bf16_to_f(hb));
}

// ---------------- preprocessing (bucket pipeline) ----------------
// pairs packed: bits 0..16 = src (N < 2^17), bits 17..25 = dst low-9 bits.

__global__ __launch_bounds__(256) void k_bcnt(const int* __restrict__ dst, int E, int NB,
                                              int* __restrict__ bucket_cnt) {
    __shared__ int lcnt[NBMAX];
    int t = threadIdx.x;
    int base = blockIdx.x * CHUNK;
    for (int i = t; i < NB; i += 256) lcnt[i] = 0;
    __syncthreads();
#pragma unroll
    for (int i = 0; i < 16; i++) {
        int e = base + i * 256 + t;
        if (e < E) atomicAdd(&lcnt[dst[e] >> BSH], 1);
    }
    __syncthreads();
    for (int i = t; i < NB; i += 256) {
        int c = lcnt[i];
        if (c) atomicAdd(&bucket_cnt[i], c);
    }
}

__global__ __launch_bounds__(256) void k_bscan(const int* __restrict__ bucket_cnt,
                                               int NB, int E, int N,
                                               int* __restrict__ bucket_off,
                                               int* __restrict__ bcur,
                                               int* __restrict__ rowstart) {
    __shared__ int sh[NBMAX];
    int t = threadIdx.x;
    int v = (t < NB) ? bucket_cnt[t] : 0;
    sh[t] = v;
    __syncthreads();
    for (int off = 1; off < NBMAX; off <<= 1) {
        int x = (t >= off) ? sh[t - off] : 0;
        __syncthreads();
        sh[t] += x;
        __syncthreads();
    }
    if (t < NB) {
        int excl = sh[t] - v;
        bucket_off[t] = excl;
        bcur[t] = excl;
    }
    if (t == 0) {
        bucket_off[NB] = E;
        rowstart[N] = E;
    }
}

// bucket-sort edges by dst>>BSH. The chunk is sorted in LDS first so the global
// pair writes are linear-per-thread (runs of ~21 edges -> near-full coalescing)
// instead of 1 scattered 4B store per lane (the R7-R9 visit model: time tracks
// distinct-line visits, so scattered 4B stores cost ~64 visits/wave-instr).
__global__ __launch_bounds__(256) void k_bucket(const int* __restrict__ src,
                                                const int* __restrict__ dst, int E, int NB,
                                                int* __restrict__ bcur,
                                                unsigned* __restrict__ pairs) {
    __shared__ int lcnt[NBMAX];
    __shared__ int loff[NBMAX];   // inclusive scan of lcnt
    __shared__ int gbase[NBMAX];
    __shared__ unsigned plds[CHUNK];
    __shared__ unsigned char blds[CHUNK];
    int t = threadIdx.x;
    int base = blockIdx.x * CHUNK;
    for (int i = t; i < NBMAX; i += 256) lcnt[i] = 0;
    __syncthreads();
    int rank[16], bid[16];
    unsigned pk[16];
#pragma unroll
    for (int i = 0; i < 16; i++) {
        int e = base + i * 256 + t;
        if (e < E) {
            int d = dst[e];
            int b = d >> BSH;
            bid[i] = b;
            pk[i] = ((unsigned)(d & BMSK) << 17) | (unsigned)src[e];
            rank[i] = atomicAdd(&lcnt[b], 1);
        } else bid[i] = -1;
    }
    __syncthreads();
    loff[t] = lcnt[t];
    __syncthreads();
    for (int off = 1; off < NBMAX; off <<= 1) {
        int x = (t >= off) ? loff[t - off] : 0;
        __syncthreads();
        loff[t] += x;
        __syncthreads();
    }
    if (t < NB) {
        int c = lcnt[t];
        gbase[t] = c ? atomicAdd(&bcur[t], c) : 0;
    }
    __syncthreads();
    // scatter into LDS, sorted by bucket
#pragma unroll
    for (int i = 0; i < 16; i++) {
        int b = bid[i];
        if (b >= 0) {
            int pos = loff[b] - lcnt[b] + rank[i];
            plds[pos] = pk[i];
            blds[pos] = (unsigned char)b;
        }
    }
    __syncthreads();
    // linear writeout: consecutive threads -> consecutive addresses within runs
    int total = min(E - base, CHUNK);
    for (int i = t; i < total; i += 256) {
        int b = blds[i];
        int local = i - (loff[b] - lcnt[b]);
        pairs[gbase[b] + local] = plds[i];
    }
}

// one block (512 threads) per bucket (512 dst nodes). Per-node count via LDS
// atomics, shfl scan -> rowstart + dinv, cursor placement into an LDS staging
// buffer, then ONE coalesced copy to csr_src (zero scattered global writes).
__global__ __launch_bounds__(512) void k_node(const unsigned* __restrict__ pairs,
                                              const int* __restrict__ bucket_off, int N,
                                              int* __restrict__ rowstart,
                                              float* __restrict__ dinv,
                                              int* __restrict__ csr_src) {
    __shared__ int cnt_l[512];
    __shared__ int cur_l[512];
    __shared__ int wsum[8];
    __shared__ int stage[NCAP];
    int t = threadIdx.x;
    int lane = t & 63, wv = t >> 6;
    int b = blockIdx.x;
    int n0 = b << BSH;
    int nn = min(512, N - n0);
    cnt_l[t] = 0;
    __syncthreads();
    int e0 = bucket_off[b], e1 = bucket_off[b + 1];
    int len = e1 - e0;
    for (int e = e0 + t; e < e1; e += 512) {
        atomicAdd(&cnt_l[pairs[e] >> 17], 1);
    }
    __syncthreads();
    int c = cnt_l[t];
    int v = c;
#pragma unroll
    for (int off = 1; off < 64; off <<= 1) {
        int x = __shfl_up(v, off);
        if (lane >= off) v += x;
    }
    if (lane == 63) wsum[wv] = v;
    __syncthreads();
    if (t < 8) {
        int wval = wsum[t];
#pragma unroll
        for (int off = 1; off < 8; off <<= 1) {
            int x = __shfl_up(wval, off);
            if (lane >= off) wval += x;
        }
        wsum[t] = wval;
    }
    __syncthreads();
    int prefix = (wv > 0) ? wsum[wv - 1] : 0;
    int start = e0 + prefix + v - c;   // global CSR start for node n0+t
    if (t < nn) {
        rowstart[n0 + t] = start;
        dinv[n0 + t] = rsqrtf((float)c + 1.0f);
    }
    if (len <= NCAP) {
        cur_l[t] = start - e0;         // local staging cursor
        __syncthreads();
        for (int e = e0 + t; e < e1; e += 512) {
            unsigned p = pairs[e];
            int r = atomicAdd(&cur_l[p >> 17], 1);
            stage[r] = (int)(p & 0x1FFFFu);
        }
        __syncthreads();
        for (int i = t; i < len; i += 512) csr_src[e0 + i] = stage[i];
    } else {  // fallback (statistically unreachable): direct scattered writes
        cur_l[t] = start;
        __syncthreads();
        for (int e = e0 + t; e < e1; e += 512) {
            unsigned p = pairs[e];
            int r = atomicAdd(&cur_l[p >> 17], 1);
            csr_src[r] = (int)(p & 0x1FFFFu);
        }
    }
}

// ---------------- W prep (all 3 weights) + bucket_cnt zeroing ----------------
__global__ __launch_bounds__(256) void k_wprep3(const float* __restrict__ W1,
                                                const float* __restrict__ W2,
                                                const float* __restrict__ W3,
                                                unsigned short* __restrict__ WH,
                                                unsigned short* __restrict__ WL,
                                                int* __restrict__ bucket_cnt) {
    if (blockIdx.x == 0 && threadIdx.x < NBMAX) bucket_cnt[threadIdx.x] = 0;
    int wi = blockIdx.x >> 6;
    int idx = (blockIdx.x & 63) * 256 + threadIdx.x;
    const float* W = (wi == 0) ? W1 : (wi == 1) ? W2 : W3;
    int j = idx & 7;
    int lane = (idx >> 3) & 63;
    int ct = (idx >> 9) & 7;
    int kc = idx >> 12;
    int k = kc * 32 + (lane >> 4) * 8 + j;
    int col = ct * 16 + (lane & 15);
    float v = W[k * 128 + col];
    unsigned short hb = bf16_rne(v);
    WH[wi * 16384 + idx] = hb;
    WL[wi * 16384 + idx] = bf16_rne(v - bf16_to_f(hb));
}

// ---------------- GEMM: U = bf16(dinv .* (A @ W)) via 3-term bf16 MFMA ----------
// R9 form (direct per-lane A loads; R10's LDS staging regressed ~9us/gemm from
// the extra barriers). A*W ~= Ah*Wh + Ah*Wl + Al*Wh; ~16 mantissa bits.

__global__ __launch_bounds__(256) void k_gemm3(const float* __restrict__ A,
                                               const unsigned short* __restrict__ WH,
                                               const unsigned short* __restrict__ WL,
                                               const float* __restrict__ dinv,
                                               unsigned short* __restrict__ U, int N) {
    int wv = threadIdx.x >> 6;
    int l = threadIdx.x & 63;
    int quad = l >> 4;
    int lm = l & 15;
    int rowBase = blockIdx.x * 128 + wv * 32;

    f32x4 acc[2][8] = {};

    int r0 = rowBase + lm;
    int r1 = rowBase + 16 + lm;

    for (int kc = 0; kc < 4; kc++) {
        int k0 = kc * 32 + quad * 8;
        float av0[8] = {}, av1[8] = {};
        if (r0 < N) {
            float4 a = *(const float4*)&A[(size_t)r0 * 128 + k0];
            float4 b = *(const float4*)&A[(size_t)r0 * 128 + k0 + 4];
            av0[0] = a.x; av0[1] = a.y; av0[2] = a.z; av0[3] = a.w;
            av0[4] = b.x; av0[5] = b.y; av0[6] = b.z; av0[7] = b.w;
        }
        if (r1 < N) {
            float4 a = *(const float4*)&A[(size_t)r1 * 128 + k0];
            float4 b = *(const float4*)&A[(size_t)r1 * 128 + k0 + 4];
            av1[0] = a.x; av1[1] = a.y; av1[2] = a.z; av1[3] = a.w;
            av1[4] = b.x; av1[5] = b.y; av1[6] = b.z; av1[7] = b.w;
        }
        short8 ah0, al0, ah1, al1;
#pragma unroll
        for (int j = 0; j < 8; j++) {
            short h, lo;
            split2(av0[j], h, lo); ah0[j] = h; al0[j] = lo;
            split2(av1[j], h, lo); ah1[j] = h; al1[j] = lo;
        }
#pragma unroll
        for (int ct = 0; ct < 8; ct++) {
            size_t fo = ((size_t)(kc * 8 + ct) * 64 + l) * 8;
            short8 wh = *(const short8*)&WH[fo];
            short8 wl = *(const short8*)&WL[fo];
            acc[0][ct] = __builtin_amdgcn_mfma_f32_16x16x32_bf16(ah0, wh, acc[0][ct], 0, 0, 0);
            acc[0][ct] = __builtin_amdgcn_mfma_f32_16x16x32_bf16(ah0, wl, acc[0][ct], 0, 0, 0);
            acc[0][ct] = __builtin_amdgcn_mfma_f32_16x16x32_bf16(al0, wh, acc[0][ct], 0, 0, 0);
            acc[1][ct] = __builtin_amdgcn_mfma_f32_16x16x32_bf16(ah1, wh, acc[1][ct], 0, 0, 0);
            acc[1][ct] = __builtin_amdgcn_mfma_f32_16x16x32_bf16(ah1, wl, acc[1][ct], 0, 0, 0);
            acc[1][ct] = __builtin_amdgcn_mfma_f32_16x16x32_bf16(al1, wh, acc[1][ct], 0, 0, 0);
        }
    }

    // epilogue: C/D map col=lane&15, row=quad*4+reg (m89-verified)
#pragma unroll
    for (int rt = 0; rt < 2; rt++) {
#pragma unroll
        for (int reg = 0; reg < 4; reg++) {
            int row = rowBase + rt * 16 + quad * 4 + reg;
            if (row < N) {
                float dv = dinv[row];
#pragma unroll
                for (int ct = 0; ct < 8; ct++) {
                    U[(size_t)row * 128 + ct * 16 + lm] = bf16_rne(dv * acc[rt][ct][reg]);
                }
            }
        }
    }
}

// ---------------- aggregation ----------------
// Pinned at ~73us/layer by distinct-row-visit throughput (R7/R8/R9 A/B):
// 1.7M visits/layer @ ~26 CU-cycles each. Structure kept from R9.

template <int RES>
__global__ __launch_bounds__(256) void k_agg(const unsigned short* __restrict__ U,
                                             const int* __restrict__ rowstart,
                                             const int* __restrict__ csr_src,
                                             const float* __restrict__ dinv,
                                             const float* __restrict__ bias,
                                             float* __restrict__ H, int N) {
    int wave = threadIdx.x >> 6;  // 0..3
    int lane = threadIdx.x & 63;
    int n = blockIdx.x * 4 + wave;
    if (n >= N) return;
    int grp = lane >> 4;   // edge group 0..3
    int li = lane & 15;    // channel octet: li*8 .. li*8+7
    int e0 = rowstart[n], e1 = rowstart[n + 1];
    int len = e1 - e0;
    int q0 = e0 + ((len * grp) >> 2);
    int q1 = e0 + ((len * (grp + 1)) >> 2);

    float a0 = 0.f, a1 = 0.f, a2 = 0.f, a3 = 0.f;
    float a4 = 0.f, a5 = 0.f, a6 = 0.f, a7 = 0.f;
    float b0 = 0.f, b1 = 0.f, b2 = 0.f, b3 = 0.f;
    float b4 = 0.f, b5 = 0.f, b6 = 0.f, b7 = 0.f;

    int e = q0;
    for (; e + 2 <= q1; e += 2) {
        int s0 = csr_src[e];
        int s1 = csr_src[e + 1];
        uint4 r0 = *(const uint4*)&U[(size_t)s0 * 128 + li * 8];
        uint4 r1 = *(const uint4*)&U[(size_t)s1 * 128 + li * 8];
        a0 += __uint_as_float(r0.x << 16);        a1 += __uint_as_float(r0.x & 0xFFFF0000u);
        a2 += __uint_as_float(r0.y << 16);        a3 += __uint_as_float(r0.y & 0xFFFF0000u);
        a4 += __uint_as_float(r0.z << 16);        a5 += __uint_as_float(r0.z & 0xFFFF0000u);
        a6 += __uint_as_float(r0.w << 16);        a7 += __uint_as_float(r0.w & 0xFFFF0000u);
        b0 += __uint_as_float(r1.x << 16);        b1 += __uint_as_float(r1.x & 0xFFFF0000u);
        b2 += __uint_as_float(r1.y << 16);        b3 += __uint_as_float(r1.y & 0xFFFF0000u);
        b4 += __uint_as_float(r1.z << 16);        b5 += __uint_as_float(r1.z & 0xFFFF0000u);
        b6 += __uint_as_float(r1.w << 16);        b7 += __uint_as_float(r1.w & 0xFFFF0000u);
    }
    if (e < q1) {
        int s0 = csr_src[e];
        uint4 r0 = *(const uint4*)&U[(size_t)s0 * 128 + li * 8];
        a0 += __uint_as_float(r0.x << 16);        a1 += __uint_as_float(r0.x & 0xFFFF0000u);
        a2 += __uint_as_float(r0.y << 16);        a3 += __uint_as_float(r0.y & 0xFFFF0000u);
        a4 += __uint_as_float(r0.z << 16);        a5 += __uint_as_float(r0.z & 0xFFFF0000u);
        a6 += __uint_as_float(r0.w << 16);        a7 += __uint_as_float(r0.w & 0xFFFF0000u);
    }
    a0 += b0; a1 += b1; a2 += b2; a3 += b3;
    a4 += b4; a5 += b5; a6 += b6; a7 += b7;

    a0 += __shfl_xor(a0, 16); a1 += __shfl_xor(a1, 16);
    a2 += __shfl_xor(a2, 16); a3 += __shfl_xor(a3, 16);
    a4 += __shfl_xor(a4, 16); a5 += __shfl_xor(a5, 16);
    a6 += __shfl_xor(a6, 16); a7 += __shfl_xor(a7, 16);
    a0 += __shfl_xor(a0, 32); a1 += __shfl_xor(a1, 32);
    a2 += __shfl_xor(a2, 32); a3 += __shfl_xor(a3, 32);
    a4 += __shfl_xor(a4, 32); a5 += __shfl_xor(a5, 32);
    a6 += __shfl_xor(a6, 32); a7 += __shfl_xor(a7, 32);

    if (grp == 0) {
        uint4 qs = *(const uint4*)&U[(size_t)n * 128 + li * 8];
        float4 bi0 = *(const float4*)&bias[li * 8];
        float4 bi1 = *(const float4*)&bias[li * 8 + 4];
        float dn = dinv[n];
        float4 o0, o1v;
        o0.x = fmaxf(dn * (a0 + __uint_as_float(qs.x << 16)) + bi0.x, 0.f);
        o0.y = fmaxf(dn * (a1 + __uint_as_float(qs.x & 0xFFFF0000u)) + bi0.y, 0.f);
        o0.z = fmaxf(dn * (a2 + __uint_as_float(qs.y << 16)) + bi0.z, 0.f);
        o0.w = fmaxf(dn * (a3 + __uint_as_float(qs.y & 0xFFFF0000u)) + bi0.w, 0.f);
        o1v.x = fmaxf(dn * (a4 + __uint_as_float(qs.z << 16)) + bi1.x, 0.f);
        o1v.y = fmaxf(dn * (a5 + __uint_as_float(qs.z & 0xFFFF0000u)) + bi1.y, 0.f);
        o1v.z = fmaxf(dn * (a6 + __uint_as_float(qs.w << 16)) + bi1.z, 0.f);
        o1v.w = fmaxf(dn * (a7 + __uint_as_float(qs.w & 0xFFFF0000u)) + bi1.w, 0.f);
        size_t hi = (size_t)n * 128 + li * 8;
        if (RES) {
            float4 h0 = *(const float4*)&H[hi];
            float4 h1 = *(const float4*)&H[hi + 4];
            o0.x += h0.x; o0.y += h0.y; o0.z += h0.z; o0.w += h0.w;
            o1v.x += h1.x; o1v.y += h1.y; o1v.z += h1.z; o1v.w += h1.w;
        }
        *(float4*)&H[hi] = o0;
        *(float4*)&H[hi + 4] = o1v;
    }
}

// ---------------- fused pooling + MLP head ----------------

__global__ __launch_bounds__(256) void k_head(const float* __restrict__ H,
                                              const int* __restrict__ batch, int N, int G,
                                              const float* __restrict__ Wf1,
                                              const float* __restrict__ bf1,
                                              const float* __restrict__ Wf2,
                                              const float* __restrict__ bf2,
                                              const float* __restrict__ Wf3,
                                              const float* __restrict__ bf3,
                                              float* __restrict__ out) {
    __shared__ float ssum[256];
    __shared__ float smax[256];
    __shared__ float grow[256];
    __shared__ float o1[128];
    __shared__ float o2[64];
    int g = blockIdx.x;
    int t = threadIdx.x;
    int i0, i1;
    {
        int lo = 0, hi = N;
        while (lo < hi) { int m = (lo + hi) >> 1; if (batch[m] < g) lo = m + 1; else hi = m; }
        i0 = lo;
        lo = i0; hi = N;
        while (lo < hi) { int m = (lo + hi) >> 1; if (batch[m] < g + 1) lo = m + 1; else hi = m; }
        i1 = lo;
    }
    int c = t & 127;
    int half = t >> 7;
    int cn = i1 - i0;
    int mid = i0 + (cn >> 1);
    int a0 = half ? mid : i0;
    int a1 = half ? i1 : mid;
    float s = 0.f, m = -3.4e38f;
    for (int i = a0; i < a1; i++) {
        float v = H[(size_t)i * 128 + c];
        s += v;
        m = fmaxf(m, v);
    }
    ssum[t] = s;
    smax[t] = m;
    __syncthreads();
    if (half == 0) {
        float st = ssum[c] + ssum[c + 128];
        float mt = fmaxf(smax[c], smax[c + 128]);
        grow[c] = (cn > 0) ? st / (float)cn : 0.f;
        grow[128 + c] = (cn > 0) ? mt : 0.f;
    }
    __syncthreads();
    if (t < 128) {
        float acc = bf1[t];
#pragma unroll 8
        for (int k = 0; k < 256; k++) acc = fmaf(grow[k], Wf1[k * 128 + t], acc);
        o1[t] = fmaxf(acc, 0.f);
    }
    __syncthreads();
    if (t < 64) {
        float a2 = bf2[t];
#pragma unroll 8
        for (int k = 0; k < 128; k++) a2 = fmaf(o1[k], Wf2[k * 64 + t], a2);
        o2[t] = fmaxf(a2, 0.f);
    }
    __syncthreads();
    if (t < 64) {
        float p = o2[t] * Wf3[t];
        for (int off = 32; off > 0; off >>= 1) p += __shfl_down(p, off);
        if (t == 0) out[g] = p + bf3[0];
    }
}

// ---------------- launch ----------------

extern "C" void kernel_launch(void* const* d_in, const int* in_sizes, int n_in,
                              void* d_out, int out_size, void* d_ws, size_t ws_size,
                              hipStream_t stream) {
    const float* x = (const float*)d_in[0];
    const int* ei = (const int*)d_in[1];
    const int* batch = (const int*)d_in[2];
    const float* W1 = (const float*)d_in[4];
    const float* b1 = (const float*)d_in[5];
    const float* W2 = (const float*)d_in[6];
    const float* b2 = (const float*)d_in[7];
    const float* W3 = (const float*)d_in[8];
    const float* b3 = (const float*)d_in[9];
    const float* Wf1 = (const float*)d_in[10];
    const float* bf1 = (const float*)d_in[11];
    const float* Wf2 = (const float*)d_in[12];
    const float* bf2 = (const float*)d_in[13];
    const float* Wf3 = (const float*)d_in[14];
    const float* bf3 = (const float*)d_in[15];

    const int N = in_sizes[0] / 128;
    const int E = in_sizes[1] / 2;
    const int G = out_size;

    const int* src = ei;
    const int* dst = ei + E;

    char* w = (char*)d_ws;
    size_t off = 0;
    auto alloc = [&](size_t bytes) -> void* {
        void* p = w + off;
        off += (bytes + 255) / 256 * 256;
        return p;
    };
    unsigned short* U = (unsigned short*)alloc((size_t)N * 128 * 2);
    float* H = (float*)alloc((size_t)N * 128 * 4);
    unsigned* pairs = (unsigned*)alloc((size_t)E * 4);   // packed (dlow<<17)|src
    int* csr_src = (int*)alloc((size_t)E * 4);
    int* rowstart = (int*)alloc((size_t)(N + 1) * 4);
    float* dinv = (float*)alloc((size_t)N * 4);
    int* bucket_cnt = (int*)alloc(NBMAX * 4);
    int* bucket_off = (int*)alloc((NBMAX + 1) * 4);
    int* bcur = (int*)alloc(NBMAX * 4);
    unsigned short* WH = (unsigned short*)alloc(3 * 16384 * 2);
    unsigned short* WL = (unsigned short*)alloc(3 * 16384 * 2);
    float* out = (float*)d_out;

    const int NB = (N + BMSK) >> BSH;
    const int ebk = (E + CHUNK - 1) / CHUNK;

    k_wprep3<<<dim3(192), dim3(256), 0, stream>>>(W1, W2, W3, WH, WL, bucket_cnt);

    k_bcnt<<<dim3(ebk), dim3(256), 0, stream>>>(dst, E, NB, bucket_cnt);
    k_bscan<<<dim3(1), dim3(NBMAX), 0, stream>>>(bucket_cnt, NB, E, N, bucket_off, bcur, rowstart);
    k_bucket<<<dim3(ebk), dim3(256), 0, stream>>>(src, dst, E, NB, bcur, pairs);
    k_node<<<dim3(NB), dim3(512), 0, stream>>>(pairs, bucket_off, N, rowstart, dinv, csr_src);

    const int gemmGrid = (N + 127) / 128;
    const int aggGrid = (N + 3) / 4;

    // conv1
    k_gemm3<<<dim3(gemmGrid), dim3(256), 0, stream>>>(x, WH, WL, dinv, U, N);
    k_agg<0><<<dim3(aggGrid), dim3(256), 0, stream>>>(U, rowstart, csr_src, dinv, b1, H, N);
    // conv2
    k_gemm3<<<dim3(gemmGrid), dim3(256), 0, stream>>>(H, WH + 16384, WL + 16384, dinv, U, N);
    k_agg<1><<<dim3(aggGrid), dim3(256), 0, stream>>>(U, rowstart, csr_src, dinv, b2, H, N);
    // conv3
    k_gemm3<<<dim3(gemmGrid), dim3(256), 0, stream>>>(H, WH + 32768, WL + 32768, dinv, U, N);
    k_agg<1><<<dim3(aggGrid), dim3(256), 0, stream>>>(U, rowstart, csr_src, dinv, b3, H, N);

    // fused pooling + MLP head
    k_head<<<dim3(G), dim3(256), 0, stream>>>(H, batch, N, G, Wf1, bf1, Wf2, bf2, Wf3, bf3, out);
}